// Round 6
// baseline (59.114 us; speedup 1.0000x reference)
//
#include <hip/hip_runtime.h>
#include <math.h>

#define CRF_B 2048
#define CRF_S 4096
#define LN2F  0.6931471805599453f

// Shared-exponent merge: A ∘= B where M = q[9] * 2^C (q renormalized so
// max|q| ~ 1). R = A.q · B.q raw (27 FMA), single pow2 renorm, C adds exactly.
#define CRF_MERGE(aq0,aq1,aq2,aq3,aq4,aq5,aq6,aq7,aq8,aC,asc,acn, \
                  bq0,bq1,bq2,bq3,bq4,bq5,bq6,bq7,bq8,bC,bsc,bcn) { \
    float r0_=aq0*bq0+aq1*bq3+aq2*bq6;                              \
    float r1_=aq0*bq1+aq1*bq4+aq2*bq7;                              \
    float r2_=aq0*bq2+aq1*bq5+aq2*bq8;                              \
    float r3_=aq3*bq0+aq4*bq3+aq5*bq6;                              \
    float r4_=aq3*bq1+aq4*bq4+aq5*bq7;                              \
    float r5_=aq3*bq2+aq4*bq5+aq5*bq8;                              \
    float r6_=aq6*bq0+aq7*bq3+aq8*bq6;                              \
    float r7_=aq6*bq1+aq7*bq4+aq8*bq7;                              \
    float r8_=aq6*bq2+aq7*bq5+aq8*bq8;                              \
    float mx_ = fmaxf(fmaxf(fmaxf(fmaxf(r0_,r1_),r2_),              \
                            fmaxf(fmaxf(r3_,r4_),r5_)),             \
                      fmaxf(fmaxf(r6_,r7_),r8_));                   \
    int ex_ = ((__float_as_int(mx_)>>23)&255)-127;                  \
    float sc_ = __int_as_float((127-ex_)<<23);                      \
    aq0=r0_*sc_; aq1=r1_*sc_; aq2=r2_*sc_;                          \
    aq3=r3_*sc_; aq4=r4_*sc_; aq5=r5_*sc_;                          \
    aq6=r6_*sc_; aq7=r7_*sc_; aq8=r8_*sc_;                          \
    aC = aC + bC + ex_;                                             \
    asc += bsc; acn += bcn; }

// ---------------------------------------------------------------------------
// One block = one batch row. 256 threads (4 waves); lane owns a 16-step chunk
// loaded directly from global into registers (192 B em + 64 B tags + 64 B
// mask). Tags/mask load+pack first (frees regs), then 12 em float4s in
// flight. Pure-VALU 16-step recursion in shared-exponent scaled-linear form,
// 6-level shfl_down log-semiring reduction, one barrier, thread 0 folds
// 3 wave-partials + epilogue.
// ---------------------------------------------------------------------------
__global__ __launch_bounds__(256, 5) void crf_row_kernel(
    const float* __restrict__ em,     // B*S*3
    const float* __restrict__ trans,  // 9
    const float* __restrict__ startt, // 3
    const float* __restrict__ endt,   // 3
    const int*   __restrict__ tags,   // B*S
    const int*   __restrict__ mask,   // B*S
    float* __restrict__ perb)         // B
{
    __shared__ float s_tr[9];         // natural-log transitions (score lookup)
    __shared__ float s_rq[4][10];     // per-wave q[9] + score
    __shared__ int   s_rc[4][2];      // per-wave C + cnt

    const int tid = threadIdx.x;      // chunk id within row (0..255)
    const int w = tid >> 6, l = tid & 63;
    const int b = blockIdx.x;
    const long cbase = (long)b * CRF_S + (long)tid * 16;  // chunk's first step

    if (tid < 9) s_tr[tid] = trans[tid];
    __syncthreads();

    // ---- tags/mask first: load 8 int4, pack to 2 scalars ----
    const int4* t4 = (const int4*)(tags + cbase);   // 64 B aligned
    int4 ta = t4[0], tb = t4[1], tc = t4[2], td = t4[3];
    const int4* m4 = (const int4*)(mask + cbase);
    int4 ma = m4[0], mb = m4[1], mc = m4[2], md = m4[3];
    int p = 0;
    if (tid > 0) p = tags[cbase - 1];

    unsigned ttag =  (unsigned)(ta.x & 3)        | ((unsigned)(ta.y & 3) << 2)
                  | ((unsigned)(ta.z & 3) << 4)  | ((unsigned)(ta.w & 3) << 6)
                  | ((unsigned)(tb.x & 3) << 8)  | ((unsigned)(tb.y & 3) << 10)
                  | ((unsigned)(tb.z & 3) << 12) | ((unsigned)(tb.w & 3) << 14)
                  | ((unsigned)(tc.x & 3) << 16) | ((unsigned)(tc.y & 3) << 18)
                  | ((unsigned)(tc.z & 3) << 20) | ((unsigned)(tc.w & 3) << 22)
                  | ((unsigned)(td.x & 3) << 24) | ((unsigned)(td.y & 3) << 26)
                  | ((unsigned)(td.z & 3) << 28) | ((unsigned)(td.w & 3) << 30);
    unsigned tmsk =  (unsigned)(ma.x != 0)        | ((unsigned)(ma.y != 0) << 1)
                  | ((unsigned)(ma.z != 0) << 2)  | ((unsigned)(ma.w != 0) << 3)
                  | ((unsigned)(mb.x != 0) << 4)  | ((unsigned)(mb.y != 0) << 5)
                  | ((unsigned)(mb.z != 0) << 6)  | ((unsigned)(mb.w != 0) << 7)
                  | ((unsigned)(mc.x != 0) << 8)  | ((unsigned)(mc.y != 0) << 9)
                  | ((unsigned)(mc.z != 0) << 10) | ((unsigned)(mc.w != 0) << 11)
                  | ((unsigned)(md.x != 0) << 12) | ((unsigned)(md.y != 0) << 13)
                  | ((unsigned)(md.z != 0) << 14) | ((unsigned)(md.w != 0) << 15);

    // ---- emissions: 12 float4 direct to registers ----
    const float4* e4 = (const float4*)(em + cbase * 3);   // 192 B, 16B-aligned
    float e[48];
    #pragma unroll
    for (int k = 0; k < 12; ++k) {
        float4 v = e4[k];
        e[4*k+0] = v.x; e[4*k+1] = v.y; e[4*k+2] = v.z; e[4*k+3] = v.w;
    }

    float Etr[9];
    #pragma unroll
    for (int k = 0; k < 9; ++k) Etr[k] = __expf(s_tr[k]);

    float q0=1.f,q1=0.f,q2=0.f, q3=0.f,q4=1.f,q5=0.f, q6=0.f,q7=0.f,q8=1.f;
    int C = 0;
    float score = 0.f; int cnt = 0;

    #pragma unroll
    for (int t = 0; t < 16; ++t) {
        float e0 = e[3*t], e1 = e[3*t+1], e2 = e[3*t+2];
        int tv = (int)((ttag >> (2*t)) & 3u);
        int mv = (int)((tmsk >> t) & 1u);
        if (mv && !((t == 0) && (tid == 0))) {   // step 0 handled in epilogue
            float X0 = __expf(e0), X1 = __expf(e1), X2 = __expf(e2);
            float n0, n1, n2;
            n0 = q0*Etr[0] + q1*Etr[3] + q2*Etr[6];
            n1 = q0*Etr[1] + q1*Etr[4] + q2*Etr[7];
            n2 = q0*Etr[2] + q1*Etr[5] + q2*Etr[8];
            q0 = n0*X0; q1 = n1*X1; q2 = n2*X2;
            n0 = q3*Etr[0] + q4*Etr[3] + q5*Etr[6];
            n1 = q3*Etr[1] + q4*Etr[4] + q5*Etr[7];
            n2 = q3*Etr[2] + q4*Etr[5] + q5*Etr[8];
            q3 = n0*X0; q4 = n1*X1; q5 = n2*X2;
            n0 = q6*Etr[0] + q7*Etr[3] + q8*Etr[6];
            n1 = q6*Etr[1] + q7*Etr[4] + q8*Etr[7];
            n2 = q6*Etr[2] + q7*Etr[5] + q8*Etr[8];
            q6 = n0*X0; q7 = n1*X1; q8 = n2*X2;
            float ev = (tv == 0) ? e0 : (tv == 1) ? e1 : e2;
            score += s_tr[p * 3 + tv] + ev;
            ++cnt;
        }
        p = tv;
        if ((t & 3) == 3) {   // shared-exponent pow2 renorm every 4 steps
            float mx = fmaxf(fmaxf(fmaxf(fmaxf(q0,q1),q2),
                                   fmaxf(fmaxf(q3,q4),q5)),
                             fmaxf(fmaxf(q6,q7),q8));
            int ex = ((__float_as_int(mx) >> 23) & 255) - 127;
            float sc = __int_as_float((127 - ex) << 23);
            q0 *= sc; q1 *= sc; q2 *= sc;
            q3 *= sc; q4 *= sc; q5 *= sc;
            q6 *= sc; q7 *= sc; q8 *= sc;
            C += ex;
        }
    }

    // ---- per-wave shfl_down reduction (lane 0 = product of wave's chunks) ----
    #pragma unroll
    for (int st = 1; st < 64; st <<= 1) {
        float nq0 = __shfl_down(q0, st), nq1 = __shfl_down(q1, st),
              nq2 = __shfl_down(q2, st), nq3 = __shfl_down(q3, st),
              nq4 = __shfl_down(q4, st), nq5 = __shfl_down(q5, st),
              nq6 = __shfl_down(q6, st), nq7 = __shfl_down(q7, st),
              nq8 = __shfl_down(q8, st);
        int   nC  = __shfl_down(C, st);
        float nsc = __shfl_down(score, st);
        int   ncn = __shfl_down(cnt, st);
        CRF_MERGE(q0,q1,q2,q3,q4,q5,q6,q7,q8,C,score,cnt,
                  nq0,nq1,nq2,nq3,nq4,nq5,nq6,nq7,nq8,nC,nsc,ncn);
    }

    if (l == 0) {
        s_rq[w][0]=q0; s_rq[w][1]=q1; s_rq[w][2]=q2;
        s_rq[w][3]=q3; s_rq[w][4]=q4; s_rq[w][5]=q5;
        s_rq[w][6]=q6; s_rq[w][7]=q7; s_rq[w][8]=q8;
        s_rq[w][9]=score;
        s_rc[w][0]=C;  s_rc[w][1]=cnt;
    }
    __syncthreads();

    if (tid == 0) {
        float a0=q0, a1=q1, a2=q2, a3=q3, a4=q4, a5=q5, a6=q6, a7=q7, a8=q8;
        float asc = score;
        int AC = C, acn = cnt;
        #pragma unroll
        for (int w2 = 1; w2 < 4; ++w2) {
            float m0=s_rq[w2][0], m1=s_rq[w2][1], m2=s_rq[w2][2],
                  m3=s_rq[w2][3], m4=s_rq[w2][4], m5=s_rq[w2][5],
                  m6=s_rq[w2][6], m7=s_rq[w2][7], m8=s_rq[w2][8];
            float msc = s_rq[w2][9];
            int mC = s_rc[w2][0], mcn = s_rc[w2][1];
            CRF_MERGE(a0,a1,a2,a3,a4,a5,a6,a7,a8,AC,asc,acn,
                      m0,m1,m2,m3,m4,m5,m6,m7,m8,mC,msc,mcn);
        }
        // ---- epilogue (tid 0 holds e[0..2] = em[b,0,:], tag0, mask0) ----
        int tg0 = (int)(ttag & 3u), mk0 = (int)(tmsk & 1u);
        float la0 = startt[0] + e[0];
        float la1 = startt[1] + e[1];
        float la2 = startt[2] + e[2];
        float am = fmaxf(fmaxf(la0, la1), la2);
        float w0  = __expf(la0 - am);
        float w1  = __expf(la1 - am);
        float w2v = __expf(la2 - am);
        float v0 = w0*a0 + w1*a3 + w2v*a6;
        float v1 = w0*a1 + w1*a4 + w2v*a7;
        float v2 = w0*a2 + w1*a5 + w2v*a8;
        float sum = v0 * __expf(endt[0]) + v1 * __expf(endt[1])
                  + v2 * __expf(endt[2]);
        float lp = am + (float)AC * LN2F + __logf(sum);

        float sc = asc + startt[tg0]
                 + ((tg0 == 0) ? e[0] : (tg0 == 1) ? e[1] : e[2]);
        int cn = acn + mk0;
        int lastidx = (cn > 0) ? (cn - 1) : 0;
        sc += endt[tags[(long)b * CRF_S + lastidx]];

        perb[b] = lp - sc;
    }
}

// ---------------------------------------------------------------------------
// Deterministic mean over B values.
// ---------------------------------------------------------------------------
__global__ __launch_bounds__(256) void crf_reduce_kernel(
    const float* __restrict__ perb, float* __restrict__ out)
{
    __shared__ float sdata[256];
    const int tid = threadIdx.x;
    float s = 0.f;
    for (int i = tid; i < CRF_B; i += 256) s += perb[i];
    sdata[tid] = s;
    __syncthreads();
    for (int off = 128; off > 0; off >>= 1) {
        if (tid < off) sdata[tid] += sdata[tid + off];
        __syncthreads();
    }
    if (tid == 0) out[0] = sdata[0] * (1.0f / (float)CRF_B);
}

extern "C" void kernel_launch(void* const* d_in, const int* in_sizes, int n_in,
                              void* d_out, int out_size, void* d_ws, size_t ws_size,
                              hipStream_t stream)
{
    const float* em     = (const float*)d_in[0];
    const float* trans  = (const float*)d_in[1];
    const float* startt = (const float*)d_in[2];
    const float* endt   = (const float*)d_in[3];
    const int*   tags   = (const int*)d_in[4];
    const int*   mask   = (const int*)d_in[5];
    float* out = (float*)d_out;

    float* perb = (float*)d_ws;   // B floats

    crf_row_kernel<<<CRF_B, 256, 0, stream>>>(
        em, trans, startt, endt, tags, mask, perb);
    crf_reduce_kernel<<<1, 256, 0, stream>>>(perb, out);
}

// Round 7
// 40.399 us; speedup vs baseline: 1.4632x; 1.4632x over previous
//
#include <hip/hip_runtime.h>
#include <math.h>

#define CRF_B 2048
#define CRF_S 4096
#define LN2F  0.6931471805599453f

// Shared-exponent merge: A ∘= B where M = q[9] * 2^C (q renormalized so
// max q ~ [1,2)). R = A.q · B.q raw (27 FMA), single pow2 renorm, C adds.
#define CRF_MERGE(aq0,aq1,aq2,aq3,aq4,aq5,aq6,aq7,aq8,aC,asc,acn, \
                  bq0,bq1,bq2,bq3,bq4,bq5,bq6,bq7,bq8,bC,bsc,bcn) { \
    float r0_=aq0*bq0+aq1*bq3+aq2*bq6;                              \
    float r1_=aq0*bq1+aq1*bq4+aq2*bq7;                              \
    float r2_=aq0*bq2+aq1*bq5+aq2*bq8;                              \
    float r3_=aq3*bq0+aq4*bq3+aq5*bq6;                              \
    float r4_=aq3*bq1+aq4*bq4+aq5*bq7;                              \
    float r5_=aq3*bq2+aq4*bq5+aq5*bq8;                              \
    float r6_=aq6*bq0+aq7*bq3+aq8*bq6;                              \
    float r7_=aq6*bq1+aq7*bq4+aq8*bq7;                              \
    float r8_=aq6*bq2+aq7*bq5+aq8*bq8;                              \
    float mx_ = fmaxf(fmaxf(fmaxf(fmaxf(r0_,r1_),r2_),              \
                            fmaxf(fmaxf(r3_,r4_),r5_)),             \
                      fmaxf(fmaxf(r6_,r7_),r8_));                   \
    int ex_ = ((__float_as_int(mx_)>>23)&255)-127;                  \
    float sc_ = __int_as_float((127-ex_)<<23);                      \
    aq0=r0_*sc_; aq1=r1_*sc_; aq2=r2_*sc_;                          \
    aq3=r3_*sc_; aq4=r4_*sc_; aq5=r5_*sc_;                          \
    aq6=r6_*sc_; aq7=r7_*sc_; aq8=r8_*sc_;                          \
    aC = aC + bC + ex_;                                             \
    asc += bsc; acn += bcn; }

// One recursion step: q (3x3, rows) <- (q · Etr) * diag(exp(e)); emission
// score select. tconst is the compile-time step index within the chunk.
#define CRF_STEP(tconst, E0, E1, E2) {                               \
    int tv_ = (int)((ttag >> (2*(tconst))) & 3u);                    \
    int mv_ = (int)((tmsk >> (tconst)) & 1u);                        \
    if (mv_ && !(((tconst) == 0) && (tid == 0))) {                   \
        float X0_ = __expf(E0), X1_ = __expf(E1), X2_ = __expf(E2);  \
        float n0_, n1_, n2_;                                         \
        n0_ = q0*Etr0 + q1*Etr3 + q2*Etr6;                           \
        n1_ = q0*Etr1 + q1*Etr4 + q2*Etr7;                           \
        n2_ = q0*Etr2 + q1*Etr5 + q2*Etr8;                           \
        q0 = n0_*X0_; q1 = n1_*X1_; q2 = n2_*X2_;                    \
        n0_ = q3*Etr0 + q4*Etr3 + q5*Etr6;                           \
        n1_ = q3*Etr1 + q4*Etr4 + q5*Etr7;                           \
        n2_ = q3*Etr2 + q4*Etr5 + q5*Etr8;                           \
        q3 = n0_*X0_; q4 = n1_*X1_; q5 = n2_*X2_;                    \
        n0_ = q6*Etr0 + q7*Etr3 + q8*Etr6;                           \
        n1_ = q6*Etr1 + q7*Etr4 + q8*Etr7;                           \
        n2_ = q6*Etr2 + q7*Etr5 + q8*Etr8;                           \
        q6 = n0_*X0_; q7 = n1_*X1_; q8 = n2_*X2_;                    \
        sem += (tv_ == 0) ? (E0) : ((tv_ == 1) ? (E1) : (E2));       \
    } }

#define CRF_RENORM() {                                               \
    float mx_ = fmaxf(fmaxf(fmaxf(fmaxf(q0,q1),q2),                  \
                            fmaxf(fmaxf(q3,q4),q5)),                 \
                      fmaxf(fmaxf(q6,q7),q8));                       \
    int ex_ = ((__float_as_int(mx_) >> 23) & 255) - 127;             \
    float sc_ = __int_as_float((127 - ex_) << 23);                   \
    q0 *= sc_; q1 *= sc_; q2 *= sc_;                                 \
    q3 *= sc_; q4 *= sc_; q5 *= sc_;                                 \
    q6 *= sc_; q7 *= sc_; q8 *= sc_;                                 \
    C += ex_; }

// ---------------------------------------------------------------------------
// One block = one batch row. 256 threads (4 waves); lane owns a 16-step
// chunk. Register software pipeline: prefetch next 3 float4 while computing
// the current 4 steps (live set ~24 floats, no local arrays -> no scratch).
// Transition-score lookups are an independent pre-pass. Shared-exponent
// scaled-linear recursion, 6-level shfl_down merge, 1 barrier, tid0 epilogue.
// ---------------------------------------------------------------------------
__global__ __launch_bounds__(256, 5) void crf_row_kernel(
    const float* __restrict__ em,     // B*S*3
    const float* __restrict__ trans,  // 9
    const float* __restrict__ startt, // 3
    const float* __restrict__ endt,   // 3
    const int*   __restrict__ tags,   // B*S
    const int*   __restrict__ mask,   // B*S
    float* __restrict__ perb)         // B
{
    __shared__ float s_tr[9];
    __shared__ float s_rq[4][10];
    __shared__ int   s_rc[4][2];

    const int tid = threadIdx.x;      // chunk id within row (0..255)
    const int w = tid >> 6, l = tid & 63;
    const int b = blockIdx.x;
    const long cbase = (long)b * CRF_S + (long)tid * 16;

    if (tid < 9) s_tr[tid] = trans[tid];
    __syncthreads();

    // ---- tags/mask: 8 int4 loads, pack to 2 scalars (transient regs) ----
    const int4* t4 = (const int4*)(tags + cbase);
    const int4* m4 = (const int4*)(mask + cbase);
    int4 ta = t4[0], tb = t4[1], tc = t4[2], td = t4[3];
    int4 ma = m4[0], mb = m4[1], mc = m4[2], md = m4[3];
    int p = 0;
    if (tid > 0) p = tags[cbase - 1];

    unsigned ttag =  (unsigned)(ta.x & 3)        | ((unsigned)(ta.y & 3) << 2)
                  | ((unsigned)(ta.z & 3) << 4)  | ((unsigned)(ta.w & 3) << 6)
                  | ((unsigned)(tb.x & 3) << 8)  | ((unsigned)(tb.y & 3) << 10)
                  | ((unsigned)(tb.z & 3) << 12) | ((unsigned)(tb.w & 3) << 14)
                  | ((unsigned)(tc.x & 3) << 16) | ((unsigned)(tc.y & 3) << 18)
                  | ((unsigned)(tc.z & 3) << 20) | ((unsigned)(tc.w & 3) << 22)
                  | ((unsigned)(td.x & 3) << 24) | ((unsigned)(td.y & 3) << 26)
                  | ((unsigned)(td.z & 3) << 28) | ((unsigned)(td.w & 3) << 30);
    unsigned tmsk =  (unsigned)(ma.x != 0)        | ((unsigned)(ma.y != 0) << 1)
                  | ((unsigned)(ma.z != 0) << 2)  | ((unsigned)(ma.w != 0) << 3)
                  | ((unsigned)(mb.x != 0) << 4)  | ((unsigned)(mb.y != 0) << 5)
                  | ((unsigned)(mb.z != 0) << 6)  | ((unsigned)(mb.w != 0) << 7)
                  | ((unsigned)(mc.x != 0) << 8)  | ((unsigned)(mc.y != 0) << 9)
                  | ((unsigned)(mc.z != 0) << 10) | ((unsigned)(mc.w != 0) << 11)
                  | ((unsigned)(md.x != 0) << 12) | ((unsigned)(md.y != 0) << 13)
                  | ((unsigned)(md.z != 0) << 14) | ((unsigned)(md.w != 0) << 15);

    // ---- transition-score pre-pass: 16 independent LDS lookups ----
    float str_sum = 0.f;
    {
        int pr = p;
        #pragma unroll
        for (int t = 0; t < 16; ++t) {
            int tv = (int)((ttag >> (2 * t)) & 3u);
            if (((tmsk >> t) & 1u) && !((t == 0) && (tid == 0)))
                str_sum += s_tr[pr * 3 + tv];
            pr = tv;
        }
    }
    int cnt = __popc(tmsk & ((tid == 0) ? 0xFFFEu : 0xFFFFu));

    float Etr0 = __expf(s_tr[0]), Etr1 = __expf(s_tr[1]), Etr2 = __expf(s_tr[2]);
    float Etr3 = __expf(s_tr[3]), Etr4 = __expf(s_tr[4]), Etr5 = __expf(s_tr[5]);
    float Etr6 = __expf(s_tr[6]), Etr7 = __expf(s_tr[7]), Etr8 = __expf(s_tr[8]);

    float q0=1.f,q1=0.f,q2=0.f, q3=0.f,q4=1.f,q5=0.f, q6=0.f,q7=0.f,q8=1.f;
    int C = 0;
    float sem = 0.f;   // emission part of gold score

    // ---- pipelined 16-step recursion: prefetch 3 float4, compute 4 steps ----
    const float4* e4 = (const float4*)(em + cbase * 3);   // 192 B, 16B-aligned
    float4 c0 = e4[0], c1 = e4[1], c2 = e4[2];
    float et0 = c0.x, et1 = c0.y, et2 = c0.z;             // em[b,chunk,0,:] for epilogue

    #pragma unroll
    for (int g = 0; g < 4; ++g) {
        float4 f0, f1, f2;
        if (g < 3) { f0 = e4[3*g+3]; f1 = e4[3*g+4]; f2 = e4[3*g+5]; }
        CRF_STEP(4*g + 0, c0.x, c0.y, c0.z);
        CRF_STEP(4*g + 1, c0.w, c1.x, c1.y);
        CRF_STEP(4*g + 2, c1.z, c1.w, c2.x);
        CRF_STEP(4*g + 3, c2.y, c2.z, c2.w);
        CRF_RENORM();
        c0 = f0; c1 = f1; c2 = f2;
    }
    float score = str_sum + sem;

    // ---- per-wave shfl_down log-semiring reduction ----
    #pragma unroll
    for (int st = 1; st < 64; st <<= 1) {
        float nq0 = __shfl_down(q0, st), nq1 = __shfl_down(q1, st),
              nq2 = __shfl_down(q2, st), nq3 = __shfl_down(q3, st),
              nq4 = __shfl_down(q4, st), nq5 = __shfl_down(q5, st),
              nq6 = __shfl_down(q6, st), nq7 = __shfl_down(q7, st),
              nq8 = __shfl_down(q8, st);
        int   nC  = __shfl_down(C, st);
        float nsc = __shfl_down(score, st);
        int   ncn = __shfl_down(cnt, st);
        CRF_MERGE(q0,q1,q2,q3,q4,q5,q6,q7,q8,C,score,cnt,
                  nq0,nq1,nq2,nq3,nq4,nq5,nq6,nq7,nq8,nC,nsc,ncn);
    }

    if (l == 0) {
        s_rq[w][0]=q0; s_rq[w][1]=q1; s_rq[w][2]=q2;
        s_rq[w][3]=q3; s_rq[w][4]=q4; s_rq[w][5]=q5;
        s_rq[w][6]=q6; s_rq[w][7]=q7; s_rq[w][8]=q8;
        s_rq[w][9]=score;
        s_rc[w][0]=C;  s_rc[w][1]=cnt;
    }
    __syncthreads();

    if (tid == 0) {
        float a0=q0, a1=q1, a2=q2, a3=q3, a4=q4, a5=q5, a6=q6, a7=q7, a8=q8;
        float asc = score;
        int AC = C, acn = cnt;
        #pragma unroll
        for (int w2 = 1; w2 < 4; ++w2) {
            float m0=s_rq[w2][0], m1=s_rq[w2][1], m2=s_rq[w2][2],
                  m3=s_rq[w2][3], m4=s_rq[w2][4], m5=s_rq[w2][5],
                  m6=s_rq[w2][6], m7=s_rq[w2][7], m8=s_rq[w2][8];
            float msc = s_rq[w2][9];
            int mC = s_rc[w2][0], mcn = s_rc[w2][1];
            CRF_MERGE(a0,a1,a2,a3,a4,a5,a6,a7,a8,AC,asc,acn,
                      m0,m1,m2,m3,m4,m5,m6,m7,m8,mC,msc,mcn);
        }
        // ---- epilogue (tid 0 holds et0..2 = em[b,0,:], tag0, mask0) ----
        int tg0 = (int)(ttag & 3u), mk0 = (int)(tmsk & 1u);
        float la0 = startt[0] + et0;
        float la1 = startt[1] + et1;
        float la2 = startt[2] + et2;
        float am = fmaxf(fmaxf(la0, la1), la2);
        float w0  = __expf(la0 - am);
        float w1  = __expf(la1 - am);
        float w2v = __expf(la2 - am);
        float v0 = w0*a0 + w1*a3 + w2v*a6;
        float v1 = w0*a1 + w1*a4 + w2v*a7;
        float v2 = w0*a2 + w1*a5 + w2v*a8;
        float sum = v0 * __expf(endt[0]) + v1 * __expf(endt[1])
                  + v2 * __expf(endt[2]);
        float lp = am + (float)AC * LN2F + __logf(sum);

        float sc = asc + startt[tg0]
                 + ((tg0 == 0) ? et0 : (tg0 == 1) ? et1 : et2);
        int cn = acn + mk0;
        int lastidx = (cn > 0) ? (cn - 1) : 0;
        sc += endt[tags[(long)b * CRF_S + lastidx]];

        perb[b] = lp - sc;
    }
}

// ---------------------------------------------------------------------------
// Deterministic mean over B values.
// ---------------------------------------------------------------------------
__global__ __launch_bounds__(256) void crf_reduce_kernel(
    const float* __restrict__ perb, float* __restrict__ out)
{
    __shared__ float sdata[256];
    const int tid = threadIdx.x;
    float s = 0.f;
    for (int i = tid; i < CRF_B; i += 256) s += perb[i];
    sdata[tid] = s;
    __syncthreads();
    for (int off = 128; off > 0; off >>= 1) {
        if (tid < off) sdata[tid] += sdata[tid + off];
        __syncthreads();
    }
    if (tid == 0) out[0] = sdata[0] * (1.0f / (float)CRF_B);
}

extern "C" void kernel_launch(void* const* d_in, const int* in_sizes, int n_in,
                              void* d_out, int out_size, void* d_ws, size_t ws_size,
                              hipStream_t stream)
{
    const float* em     = (const float*)d_in[0];
    const float* trans  = (const float*)d_in[1];
    const float* startt = (const float*)d_in[2];
    const float* endt   = (const float*)d_in[3];
    const int*   tags   = (const int*)d_in[4];
    const int*   mask   = (const int*)d_in[5];
    float* out = (float*)d_out;

    float* perb = (float*)d_ws;   // B floats

    crf_row_kernel<<<CRF_B, 256, 0, stream>>>(
        em, trans, startt, endt, tags, mask, perb);
    crf_reduce_kernel<<<1, 256, 0, stream>>>(perb, out);
}

// Round 8
// 38.511 us; speedup vs baseline: 1.5350x; 1.0490x over previous
//
#include <hip/hip_runtime.h>
#include <math.h>

#define CRF_B 2048
#define CRF_S 4096
#define LN2F  0.6931471805599453f

// Shared-exponent merge: A ∘= B where M = q[9] * 2^C (q renormalized so
// max q ~ [1,2)). R = A.q · B.q raw (27 FMA), single pow2 renorm, C adds.
#define CRF_MERGE(aq0,aq1,aq2,aq3,aq4,aq5,aq6,aq7,aq8,aC,asc,acn, \
                  bq0,bq1,bq2,bq3,bq4,bq5,bq6,bq7,bq8,bC,bsc,bcn) { \
    float r0_=aq0*bq0+aq1*bq3+aq2*bq6;                              \
    float r1_=aq0*bq1+aq1*bq4+aq2*bq7;                              \
    float r2_=aq0*bq2+aq1*bq5+aq2*bq8;                              \
    float r3_=aq3*bq0+aq4*bq3+aq5*bq6;                              \
    float r4_=aq3*bq1+aq4*bq4+aq5*bq7;                              \
    float r5_=aq3*bq2+aq4*bq5+aq5*bq8;                              \
    float r6_=aq6*bq0+aq7*bq3+aq8*bq6;                              \
    float r7_=aq6*bq1+aq7*bq4+aq8*bq7;                              \
    float r8_=aq6*bq2+aq7*bq5+aq8*bq8;                              \
    float mx_ = fmaxf(fmaxf(fmaxf(fmaxf(r0_,r1_),r2_),              \
                            fmaxf(fmaxf(r3_,r4_),r5_)),             \
                      fmaxf(fmaxf(r6_,r7_),r8_));                   \
    int ex_ = ((__float_as_int(mx_)>>23)&255)-127;                  \
    float sc_ = __int_as_float((127-ex_)<<23);                      \
    aq0=r0_*sc_; aq1=r1_*sc_; aq2=r2_*sc_;                          \
    aq3=r3_*sc_; aq4=r4_*sc_; aq5=r5_*sc_;                          \
    aq6=r6_*sc_; aq7=r7_*sc_; aq8=r8_*sc_;                          \
    aC = aC + bC + ex_;                                             \
    asc += bsc; acn += bcn; }

// One recursion step: q (3x3, rows) <- (q · Etr) * diag(exp(e)); emission
// score select. tconst is the compile-time step index within the chunk.
#define CRF_STEP(tconst, E0, E1, E2) {                               \
    int tv_ = (int)((ttag >> (2*(tconst))) & 3u);                    \
    int mv_ = (int)((tmsk >> (tconst)) & 1u);                        \
    if (mv_ && !(((tconst) == 0) && (tid == 0))) {                   \
        float X0_ = __expf(E0), X1_ = __expf(E1), X2_ = __expf(E2);  \
        float n0_, n1_, n2_;                                         \
        n0_ = q0*Etr0 + q1*Etr3 + q2*Etr6;                           \
        n1_ = q0*Etr1 + q1*Etr4 + q2*Etr7;                           \
        n2_ = q0*Etr2 + q1*Etr5 + q2*Etr8;                           \
        q0 = n0_*X0_; q1 = n1_*X1_; q2 = n2_*X2_;                    \
        n0_ = q3*Etr0 + q4*Etr3 + q5*Etr6;                           \
        n1_ = q3*Etr1 + q4*Etr4 + q5*Etr7;                           \
        n2_ = q3*Etr2 + q4*Etr5 + q5*Etr8;                           \
        q3 = n0_*X0_; q4 = n1_*X1_; q5 = n2_*X2_;                    \
        n0_ = q6*Etr0 + q7*Etr3 + q8*Etr6;                           \
        n1_ = q6*Etr1 + q7*Etr4 + q8*Etr7;                           \
        n2_ = q6*Etr2 + q7*Etr5 + q8*Etr8;                           \
        q6 = n0_*X0_; q7 = n1_*X1_; q8 = n2_*X2_;                    \
        sem += (tv_ == 0) ? (E0) : ((tv_ == 1) ? (E1) : (E2));       \
    } }

#define CRF_RENORM() {                                               \
    float mx_ = fmaxf(fmaxf(fmaxf(fmaxf(q0,q1),q2),                  \
                            fmaxf(fmaxf(q3,q4),q5)),                 \
                      fmaxf(fmaxf(q6,q7),q8));                       \
    int ex_ = ((__float_as_int(mx_) >> 23) & 255) - 127;             \
    float sc_ = __int_as_float((127 - ex_) << 23);                   \
    q0 *= sc_; q1 *= sc_; q2 *= sc_;                                 \
    q3 *= sc_; q4 *= sc_; q5 *= sc_;                                 \
    q6 *= sc_; q7 *= sc_; q8 *= sc_;                                 \
    C += ex_; }

// ---------------------------------------------------------------------------
// One block = one batch row. 256 threads (4 waves); lane owns a 16-step
// chunk. ALL global loads for the chunk (12 em float4 + 8 tag/mask int4 +
// prev-tag) are issued up front into named registers -> one latency exposure
// per chunk, ~48 loads in flight per SIMD. Then a pure-register 16-step
// recursion in shared-exponent scaled-linear form, 6-level shfl_down
// log-semiring merge, 1 barrier, tid0 folds 3 wave-partials + epilogue.
// ---------------------------------------------------------------------------
__global__ __launch_bounds__(256, 4) void crf_row_kernel(
    const float* __restrict__ em,     // B*S*3
    const float* __restrict__ trans,  // 9
    const float* __restrict__ startt, // 3
    const float* __restrict__ endt,   // 3
    const int*   __restrict__ tags,   // B*S
    const int*   __restrict__ mask,   // B*S
    float* __restrict__ perb)         // B
{
    __shared__ float s_tr[9];
    __shared__ float s_rq[4][10];
    __shared__ int   s_rc[4][2];

    const int tid = threadIdx.x;      // chunk id within row (0..255)
    const int w = tid >> 6, l = tid & 63;
    const int b = blockIdx.x;
    const long cbase = (long)b * CRF_S + (long)tid * 16;

    if (tid < 9) s_tr[tid] = trans[tid];

    // ---- issue ALL chunk loads up front (independent, stay in flight) ----
    const float4* e4 = (const float4*)(em + cbase * 3);   // 192 B, 16B-aligned
    float4 ea0 = e4[0], ea1 = e4[1], ea2  = e4[2],  ea3  = e4[3];
    float4 ea4 = e4[4], ea5 = e4[5], ea6  = e4[6],  ea7  = e4[7];
    float4 ea8 = e4[8], ea9 = e4[9], ea10 = e4[10], ea11 = e4[11];
    const int4* t4 = (const int4*)(tags + cbase);
    const int4* m4 = (const int4*)(mask + cbase);
    int4 ta = t4[0], tb = t4[1], tc = t4[2], td = t4[3];
    int4 ma = m4[0], mb = m4[1], mc = m4[2], md = m4[3];
    int p = 0;
    if (tid > 0) p = tags[cbase - 1];

    __syncthreads();   // s_tr visible

    // ---- pack tags (2b) and mask (1b) into scalars (frees the int4 regs) ----
    unsigned ttag =  (unsigned)(ta.x & 3)        | ((unsigned)(ta.y & 3) << 2)
                  | ((unsigned)(ta.z & 3) << 4)  | ((unsigned)(ta.w & 3) << 6)
                  | ((unsigned)(tb.x & 3) << 8)  | ((unsigned)(tb.y & 3) << 10)
                  | ((unsigned)(tb.z & 3) << 12) | ((unsigned)(tb.w & 3) << 14)
                  | ((unsigned)(tc.x & 3) << 16) | ((unsigned)(tc.y & 3) << 18)
                  | ((unsigned)(tc.z & 3) << 20) | ((unsigned)(tc.w & 3) << 22)
                  | ((unsigned)(td.x & 3) << 24) | ((unsigned)(td.y & 3) << 26)
                  | ((unsigned)(td.z & 3) << 28) | ((unsigned)(td.w & 3) << 30);
    unsigned tmsk =  (unsigned)(ma.x != 0)        | ((unsigned)(ma.y != 0) << 1)
                  | ((unsigned)(ma.z != 0) << 2)  | ((unsigned)(ma.w != 0) << 3)
                  | ((unsigned)(mb.x != 0) << 4)  | ((unsigned)(mb.y != 0) << 5)
                  | ((unsigned)(mb.z != 0) << 6)  | ((unsigned)(mb.w != 0) << 7)
                  | ((unsigned)(mc.x != 0) << 8)  | ((unsigned)(mc.y != 0) << 9)
                  | ((unsigned)(mc.z != 0) << 10) | ((unsigned)(mc.w != 0) << 11)
                  | ((unsigned)(md.x != 0) << 12) | ((unsigned)(md.y != 0) << 13)
                  | ((unsigned)(md.z != 0) << 14) | ((unsigned)(md.w != 0) << 15);

    // ---- transition-score pre-pass: 16 independent LDS lookups ----
    float str_sum = 0.f;
    {
        int pr = p;
        #pragma unroll
        for (int t = 0; t < 16; ++t) {
            int tv = (int)((ttag >> (2 * t)) & 3u);
            if (((tmsk >> t) & 1u) && !((t == 0) && (tid == 0)))
                str_sum += s_tr[pr * 3 + tv];
            pr = tv;
        }
    }
    int cnt = __popc(tmsk & ((tid == 0) ? 0xFFFEu : 0xFFFFu));

    float Etr0 = __expf(s_tr[0]), Etr1 = __expf(s_tr[1]), Etr2 = __expf(s_tr[2]);
    float Etr3 = __expf(s_tr[3]), Etr4 = __expf(s_tr[4]), Etr5 = __expf(s_tr[5]);
    float Etr6 = __expf(s_tr[6]), Etr7 = __expf(s_tr[7]), Etr8 = __expf(s_tr[8]);

    float q0=1.f,q1=0.f,q2=0.f, q3=0.f,q4=1.f,q5=0.f, q6=0.f,q7=0.f,q8=1.f;
    int C = 0;
    float sem = 0.f;   // emission part of gold score

    float et0 = ea0.x, et1 = ea0.y, et2 = ea0.z;   // em[b,chunk,0,:] (epilogue)

    CRF_STEP( 0, ea0.x, ea0.y, ea0.z);
    CRF_STEP( 1, ea0.w, ea1.x, ea1.y);
    CRF_STEP( 2, ea1.z, ea1.w, ea2.x);
    CRF_STEP( 3, ea2.y, ea2.z, ea2.w);
    CRF_RENORM();
    CRF_STEP( 4, ea3.x, ea3.y, ea3.z);
    CRF_STEP( 5, ea3.w, ea4.x, ea4.y);
    CRF_STEP( 6, ea4.z, ea4.w, ea5.x);
    CRF_STEP( 7, ea5.y, ea5.z, ea5.w);
    CRF_RENORM();
    CRF_STEP( 8, ea6.x, ea6.y, ea6.z);
    CRF_STEP( 9, ea6.w, ea7.x, ea7.y);
    CRF_STEP(10, ea7.z, ea7.w, ea8.x);
    CRF_STEP(11, ea8.y, ea8.z, ea8.w);
    CRF_RENORM();
    CRF_STEP(12, ea9.x, ea9.y, ea9.z);
    CRF_STEP(13, ea9.w, ea10.x, ea10.y);
    CRF_STEP(14, ea10.z, ea10.w, ea11.x);
    CRF_STEP(15, ea11.y, ea11.z, ea11.w);
    CRF_RENORM();

    float score = str_sum + sem;

    // ---- per-wave shfl_down log-semiring reduction ----
    #pragma unroll
    for (int st = 1; st < 64; st <<= 1) {
        float nq0 = __shfl_down(q0, st), nq1 = __shfl_down(q1, st),
              nq2 = __shfl_down(q2, st), nq3 = __shfl_down(q3, st),
              nq4 = __shfl_down(q4, st), nq5 = __shfl_down(q5, st),
              nq6 = __shfl_down(q6, st), nq7 = __shfl_down(q7, st),
              nq8 = __shfl_down(q8, st);
        int   nC  = __shfl_down(C, st);
        float nsc = __shfl_down(score, st);
        int   ncn = __shfl_down(cnt, st);
        CRF_MERGE(q0,q1,q2,q3,q4,q5,q6,q7,q8,C,score,cnt,
                  nq0,nq1,nq2,nq3,nq4,nq5,nq6,nq7,nq8,nC,nsc,ncn);
    }

    if (l == 0) {
        s_rq[w][0]=q0; s_rq[w][1]=q1; s_rq[w][2]=q2;
        s_rq[w][3]=q3; s_rq[w][4]=q4; s_rq[w][5]=q5;
        s_rq[w][6]=q6; s_rq[w][7]=q7; s_rq[w][8]=q8;
        s_rq[w][9]=score;
        s_rc[w][0]=C;  s_rc[w][1]=cnt;
    }
    __syncthreads();

    if (tid == 0) {
        float a0=q0, a1=q1, a2=q2, a3=q3, a4=q4, a5=q5, a6=q6, a7=q7, a8=q8;
        float asc = score;
        int AC = C, acn = cnt;
        #pragma unroll
        for (int w2 = 1; w2 < 4; ++w2) {
            float m0=s_rq[w2][0], m1=s_rq[w2][1], m2=s_rq[w2][2],
                  m3=s_rq[w2][3], m4=s_rq[w2][4], m5=s_rq[w2][5],
                  m6=s_rq[w2][6], m7=s_rq[w2][7], m8=s_rq[w2][8];
            float msc = s_rq[w2][9];
            int mC = s_rc[w2][0], mcn = s_rc[w2][1];
            CRF_MERGE(a0,a1,a2,a3,a4,a5,a6,a7,a8,AC,asc,acn,
                      m0,m1,m2,m3,m4,m5,m6,m7,m8,mC,msc,mcn);
        }
        // ---- epilogue (tid 0 holds et0..2 = em[b,0,:], tag0, mask0) ----
        int tg0 = (int)(ttag & 3u), mk0 = (int)(tmsk & 1u);
        float la0 = startt[0] + et0;
        float la1 = startt[1] + et1;
        float la2 = startt[2] + et2;
        float am = fmaxf(fmaxf(la0, la1), la2);
        float w0  = __expf(la0 - am);
        float w1  = __expf(la1 - am);
        float w2v = __expf(la2 - am);
        float v0 = w0*a0 + w1*a3 + w2v*a6;
        float v1 = w0*a1 + w1*a4 + w2v*a7;
        float v2 = w0*a2 + w1*a5 + w2v*a8;
        float sum = v0 * __expf(endt[0]) + v1 * __expf(endt[1])
                  + v2 * __expf(endt[2]);
        float lp = am + (float)AC * LN2F + __logf(sum);

        float sc = asc + startt[tg0]
                 + ((tg0 == 0) ? et0 : (tg0 == 1) ? et1 : et2);
        int cn = acn + mk0;
        int lastidx = (cn > 0) ? (cn - 1) : 0;
        sc += endt[tags[(long)b * CRF_S + lastidx]];

        perb[b] = lp - sc;
    }
}

// ---------------------------------------------------------------------------
// Deterministic mean over B values.
// ---------------------------------------------------------------------------
__global__ __launch_bounds__(256) void crf_reduce_kernel(
    const float* __restrict__ perb, float* __restrict__ out)
{
    __shared__ float sdata[256];
    const int tid = threadIdx.x;
    float s = 0.f;
    for (int i = tid; i < CRF_B; i += 256) s += perb[i];
    sdata[tid] = s;
    __syncthreads();
    for (int off = 128; off > 0; off >>= 1) {
        if (tid < off) sdata[tid] += sdata[tid + off];
        __syncthreads();
    }
    if (tid == 0) out[0] = sdata[0] * (1.0f / (float)CRF_B);
}

extern "C" void kernel_launch(void* const* d_in, const int* in_sizes, int n_in,
                              void* d_out, int out_size, void* d_ws, size_t ws_size,
                              hipStream_t stream)
{
    const float* em     = (const float*)d_in[0];
    const float* trans  = (const float*)d_in[1];
    const float* startt = (const float*)d_in[2];
    const float* endt   = (const float*)d_in[3];
    const int*   tags   = (const int*)d_in[4];
    const int*   mask   = (const int*)d_in[5];
    float* out = (float*)d_out;

    float* perb = (float*)d_ws;   // B floats

    crf_row_kernel<<<CRF_B, 256, 0, stream>>>(
        em, trans, startt, endt, tags, mask, perb);
    crf_reduce_kernel<<<1, 256, 0, stream>>>(perb, out);
}